// Round 5
// baseline (329.693 us; speedup 1.0000x reference)
//
#include <hip/hip_runtime.h>
#include <stdint.h>

// GAT layer, B=8, N=2048, D=128, fp32 in/out.
// prep_wt: W -> W^T bf16 hi/lo (fc B-fragments).
// fc:      h = (x*mask)@W via 3-term bf16-split MFMA -> hT bf16 [B][D][N],
//          e_l, e_r fp32.
// attn:    per-block ballot-compressed adj load phase (coalesced, one-pass)
//          -> 4KB LDS bitmask; then flash attention (4-way split-K, MFMA
//          bf16 PV) touching only LDS/L2 data; LDS merge + LayerNorm.

#define BB 8
#define NN 2048
#define DD 128
#define GAT_NEG_INF -10000.0f
#define LN_EPS 1e-5f

typedef __attribute__((ext_vector_type(8))) short short8;
typedef __attribute__((ext_vector_type(4))) float f32x4;

__device__ __forceinline__ unsigned pk_bf16(float a, float b) {
    unsigned ua = __float_as_uint(a); ua += 0x7FFFu + ((ua >> 16) & 1u);
    unsigned ub = __float_as_uint(b); ub += 0x7FFFu + ((ub >> 16) & 1u);
    return (ua >> 16) | (ub & 0xFFFF0000u);
}
__device__ __forceinline__ unsigned short bf16_rtn(float a) {
    unsigned ua = __float_as_uint(a);
    return (unsigned short)((ua + 0x7FFFu + ((ua >> 16) & 1u)) >> 16);
}

// ---------------------------------------------------------------------------
// prep_wt: WThi/WTlo[n][k] = bf16 split of W[k][n].
// ---------------------------------------------------------------------------
__global__ void prep_wt(const float* __restrict__ W,
                        unsigned short* __restrict__ WThi,
                        unsigned short* __restrict__ WTlo)
{
    int idx = blockIdx.x * 256 + threadIdx.x;
    int k = idx >> 7, n = idx & 127;
    float w = W[idx];
    unsigned short hi = bf16_rtn(w);
    float hif = __uint_as_float((unsigned)hi << 16);
    WThi[n * DD + k] = hi;
    WTlo[n * DD + k] = bf16_rtn(w - hif);
}

// ---------------------------------------------------------------------------
// fc: grid = BB*(NN/64) = 256 blocks (b = blk&7), block 256 = 4 waves.
// ---------------------------------------------------------------------------
__global__ __launch_bounds__(256) void fc_kernel(
    const float* __restrict__ x, const int* __restrict__ mask,
    const unsigned short* __restrict__ WThi, const unsigned short* __restrict__ WTlo,
    const float* __restrict__ a_l, const float* __restrict__ a_r,
    unsigned short* __restrict__ hT, float* __restrict__ el, float* __restrict__ er)
{
    const int t    = threadIdx.x;
    const int wv   = t >> 6;
    const int lane = t & 63;
    const int col  = lane & 15;
    const int grp  = lane >> 4;
    const int b    = blockIdx.x & 7;
    const int it   = blockIdx.x >> 3;
    const int i0   = it * 64 + wv * 16;

    const float* xrow = x + ((size_t)(b * NN + i0 + col)) * DD + grp * 8;
    const float  mm   = (float)mask[b * NN + i0 + col];

    f32x4 acc[8];
#pragma unroll
    for (int nb = 0; nb < 8; ++nb) acc[nb] = (f32x4)0.f;

    union AU { unsigned u[4]; short8 v; };
    union BU { int4 q; short8 v; };

#pragma unroll
    for (int ks = 0; ks < 4; ++ks) {
        float4 xa = *(const float4*)(xrow + ks * 32);
        float4 xb = *(const float4*)(xrow + ks * 32 + 4);
        float xv[8] = {xa.x, xa.y, xa.z, xa.w, xb.x, xb.y, xb.z, xb.w};
        unsigned short hi[8]; float lo[8];
#pragma unroll
        for (int u = 0; u < 8; ++u) {
            float v = xv[u] * mm;
            hi[u] = bf16_rtn(v);
            lo[u] = v - __uint_as_float((unsigned)hi[u] << 16);
        }
        AU Ahi, Alo;
#pragma unroll
        for (int j = 0; j < 4; ++j) {
            Ahi.u[j] = (unsigned)hi[2 * j] | ((unsigned)hi[2 * j + 1] << 16);
            Alo.u[j] = pk_bf16(lo[2 * j], lo[2 * j + 1]);
        }
#pragma unroll
        for (int nb = 0; nb < 8; ++nb) {
            BU Bhi, Blo;
            Bhi.q = *(const int4*)(WThi + (nb * 16 + col) * DD + ks * 32 + grp * 8);
            Blo.q = *(const int4*)(WTlo + (nb * 16 + col) * DD + ks * 32 + grp * 8);
            acc[nb] = __builtin_amdgcn_mfma_f32_16x16x32_bf16(Ahi.v, Bhi.v, acc[nb], 0, 0, 0);
            acc[nb] = __builtin_amdgcn_mfma_f32_16x16x32_bf16(Alo.v, Bhi.v, acc[nb], 0, 0, 0);
            acc[nb] = __builtin_amdgcn_mfma_f32_16x16x32_bf16(Ahi.v, Blo.v, acc[nb], 0, 0, 0);
        }
    }

    float sl[4] = {0.f, 0.f, 0.f, 0.f}, sr[4] = {0.f, 0.f, 0.f, 0.f};
#pragma unroll
    for (int nb = 0; nb < 8; ++nb) {
        float alv = a_l[nb * 16 + col];
        float arv = a_r[nb * 16 + col];
#pragma unroll
        for (int reg = 0; reg < 4; ++reg) {
            sl[reg] += acc[nb][reg] * alv;
            sr[reg] += acc[nb][reg] * arv;
        }
    }
#pragma unroll
    for (int off = 1; off < 16; off <<= 1)
#pragma unroll
        for (int reg = 0; reg < 4; ++reg) {
            sl[reg] += __shfl_xor(sl[reg], off, 64);
            sr[reg] += __shfl_xor(sr[reg], off, 64);
        }
    if (col == 0) {
#pragma unroll
        for (int reg = 0; reg < 4; ++reg) {
            el[b * NN + i0 + grp * 4 + reg] = sl[reg];
            er[b * NN + i0 + grp * 4 + reg] = sr[reg];
        }
    }

#pragma unroll
    for (int nb = 0; nb < 8; ++nb) {
        unsigned p01 = pk_bf16(acc[nb][0], acc[nb][1]);
        unsigned p23 = pk_bf16(acc[nb][2], acc[nb][3]);
        *(uint2*)(hT + ((size_t)(b * DD + nb * 16 + col)) * NN + i0 + grp * 4) =
            make_uint2(p01, p23);
    }
}

// ---------------------------------------------------------------------------
// attn: grid = BB*(NN/16) = 1024 blocks (b = blk&7), block 256 = 4 waves.
// Phase 1: ballot-compress adj rows i0..i0+15 (x mask_i, mask_j) into
//          bitsS[16][33] u64 in LDS. Lane l reads adj[row][chunk*64+l]
//          (256B coalesced per instruction); 128 independent loads/wave.
// Phase 2: flash attention. Wave wv: j in [wv*512, wv*512+512), 8 tiles.
//          K-loop data: bitsS (LDS), er (L1), hT (L2). No HBM.
// ---------------------------------------------------------------------------
__global__ __launch_bounds__(256, 4) void attn_kernel(
    const float* __restrict__ x, const int* __restrict__ adj,
    const int* __restrict__ mask, const unsigned short* __restrict__ hT,
    const float* __restrict__ el, const float* __restrict__ er,
    const float* __restrict__ gamma, const float* __restrict__ beta,
    float* __restrict__ outp)
{
    __shared__ __align__(16) float macc[4][16][132];        // 33.8 KB
    __shared__ float mls[4][16][2];
    __shared__ unsigned long long bitsS[16][33];            // 4.2 KB

    const int t    = threadIdx.x;
    const int wv   = t >> 6;
    const int lane = t & 63;
    const int row  = lane & 15;
    const int grp  = lane >> 4;
    const int b    = blockIdx.x & 7;
    const int it   = blockIdx.x >> 3;
    const int i0   = it * 16;
    const int gi   = i0 + row;
    const int j0   = wv * 512;

    const int*   mk_b    = mask + b * NN;
    const int*   adj_blk = adj + ((size_t)(b * NN + i0)) * NN;

    // ---- Phase 1: ballot-compress adj into LDS bits ----
#pragma unroll
    for (int batch = 0; batch < 2; ++batch) {
        const int base = wv * 128 + batch * 64;   // round base, 0..511
        unsigned long long myword = 0ull;
#pragma unroll
        for (int r = 0; r < 64; ++r) {
            const int g     = base + r;
            const int rrow  = g >> 5;         // 0..15
            const int chunk = g & 31;         // 0..31
            int a  = adj_blk[(size_t)rrow * NN + chunk * 64 + lane];
            int mj = mk_b[chunk * 64 + lane];
            unsigned long long bal = __ballot(a & mj);
            if (lane == r) myword = bal;
        }
        const int g = base + lane;
        const int rrow = g >> 5, chunk = g & 31;
        bitsS[rrow][chunk] = mk_b[i0 + rrow] ? myword : 0ull;
    }

    const float el_r = el[b * NN + gi];
    const float* er_w = er + b * NN + j0;
    const unsigned short* hT_b = hT + (size_t)b * DD * NN;

    f32x4 acc[8];
#pragma unroll
    for (int nb = 0; nb < 8; ++nb) acc[nb] = (f32x4)0.f;
    float m_run = -3.0e38f, l_run = 0.f;

    __syncthreads();

    union BU { int4 q; short8 v; };
    union AU { unsigned u[4]; short8 v; };

#pragma unroll 1
    for (int jt = 0; jt < 8; ++jt) {
        // B-fragment loads (L2-resident hT)
        BU bf[16];
        {
            const int jb = j0 + jt * 64 + grp * 8;
#pragma unroll
            for (int s = 0; s < 2; ++s)
#pragma unroll
                for (int nb = 0; nb < 8; ++nb)
                    bf[s * 8 + nb].q = *(const int4*)(hT_b
                        + (size_t)(nb * 16 + row) * NN + jb + s * 32);
        }

        const int jb = jt * 64 + grp * 8;
        float4 e0 = *(const float4*)(er_w + jb);
        float4 e1 = *(const float4*)(er_w + jb + 4);
        float4 e2 = *(const float4*)(er_w + jb + 32);
        float4 e3 = *(const float4*)(er_w + jb + 36);

        unsigned long long w = bitsS[row][wv * 8 + jt];
        unsigned lo = (unsigned)(w & 0xffffffffu);
        unsigned hi = (unsigned)(w >> 32);
        unsigned b16 = ((lo >> (grp * 8)) & 0xffu) | ((((hi >> (grp * 8)) & 0xffu)) << 8);

        float ev[16] = {e0.x,e0.y,e0.z,e0.w, e1.x,e1.y,e1.z,e1.w,
                        e2.x,e2.y,e2.z,e2.w, e3.x,e3.y,e3.z,e3.w};
        float ss[16];
        float tmax = -3.0e38f;
#pragma unroll
        for (int u = 0; u < 16; ++u) {
            float e = el_r + ev[u];
            e = fmaxf(e, 0.2f * e);                 // LeakyReLU
            ss[u] = ((b16 >> u) & 1u) ? e : GAT_NEG_INF;
            tmax = fmaxf(tmax, ss[u]);
        }
        tmax = fmaxf(tmax, __shfl_xor(tmax, 16, 64));
        tmax = fmaxf(tmax, __shfl_xor(tmax, 32, 64));
        float m_new = fmaxf(m_run, tmax);
        float al    = __expf(m_run - m_new);
        float p[16];
        float psum = 0.f;
#pragma unroll
        for (int u = 0; u < 16; ++u) {
            p[u] = __expf(ss[u] - m_new);
            psum += p[u];
        }
        psum += __shfl_xor(psum, 16, 64);
        psum += __shfl_xor(psum, 32, 64);
        l_run = l_run * al + psum;
        m_run = m_new;

        float alr[4];
#pragma unroll
        for (int reg = 0; reg < 4; ++reg) alr[reg] = __shfl(al, grp * 4 + reg, 64);
#pragma unroll
        for (int nb = 0; nb < 8; ++nb) {
            acc[nb][0] *= alr[0]; acc[nb][1] *= alr[1];
            acc[nb][2] *= alr[2]; acc[nb][3] *= alr[3];
        }

        AU A0, A1;
#pragma unroll
        for (int k = 0; k < 4; ++k) {
            A0.u[k] = pk_bf16(p[2 * k],     p[2 * k + 1]);
            A1.u[k] = pk_bf16(p[8 + 2 * k], p[8 + 2 * k + 1]);
        }
#pragma unroll
        for (int nb = 0; nb < 8; ++nb)
            acc[nb] = __builtin_amdgcn_mfma_f32_16x16x32_bf16(A0.v, bf[nb].v, acc[nb], 0, 0, 0);
#pragma unroll
        for (int nb = 0; nb < 8; ++nb)
            acc[nb] = __builtin_amdgcn_mfma_f32_16x16x32_bf16(A1.v, bf[8 + nb].v, acc[nb], 0, 0, 0);
    }

    // ---- write partials to LDS ----
    if (grp == 0) { mls[wv][row][0] = m_run; mls[wv][row][1] = l_run; }
#pragma unroll
    for (int nb = 0; nb < 8; ++nb)
#pragma unroll
        for (int reg = 0; reg < 4; ++reg)
            macc[wv][grp * 4 + reg][nb * 16 + row] = acc[nb][reg];
    __syncthreads();

    // ---- merge + residual + mask + LayerNorm; wave wv owns rows wv*4..+3 ----
    const float g0  = gamma[2 * lane], g1 = gamma[2 * lane + 1];
    const float be0 = beta[2 * lane],  be1 = beta[2 * lane + 1];
#pragma unroll
    for (int q = 0; q < 4; ++q) {
        const int r  = wv * 4 + q;
        const int gir = i0 + r;
        float m0 = mls[0][r][0], m1 = mls[1][r][0], m2 = mls[2][r][0], m3 = mls[3][r][0];
        float m_f = fmaxf(fmaxf(m0, m1), fmaxf(m2, m3));
        float sc0 = __expf(m0 - m_f), sc1 = __expf(m1 - m_f);
        float sc2 = __expf(m2 - m_f), sc3 = __expf(m3 - m_f);
        float l_f = mls[0][r][1] * sc0 + mls[1][r][1] * sc1
                  + mls[2][r][1] * sc2 + mls[3][r][1] * sc3;
        float inv = 1.0f / l_f;
        float2 v0 = *(const float2*)&macc[0][r][2 * lane];
        float2 v1 = *(const float2*)&macc[1][r][2 * lane];
        float2 v2 = *(const float2*)&macc[2][r][2 * lane];
        float2 v3 = *(const float2*)&macc[3][r][2 * lane];
        float ox = v0.x * sc0 + v1.x * sc1 + v2.x * sc2 + v3.x * sc3;
        float oy = v0.y * sc0 + v1.y * sc1 + v2.y * sc2 + v3.y * sc3;

        float mq = (float)mk_b[gir];
        float2 xv = *(const float2*)(x + ((size_t)(b * NN + gir)) * DD + 2 * lane);
        float w0 = (ox * inv + xv.x) * mq;
        float w1 = (oy * inv + xv.y) * mq;

        float s1 = w0 + w1, s2 = w0 * w0 + w1 * w1;
#pragma unroll
        for (int off = 32; off; off >>= 1) {
            s1 += __shfl_xor(s1, off, 64);
            s2 += __shfl_xor(s2, off, 64);
        }
        float mu  = s1 * (1.0f / DD);
        float var = s2 * (1.0f / DD) - mu * mu;
        float rsd = rsqrtf(var + LN_EPS);
        *(float2*)(outp + ((size_t)(b * NN + gir)) * DD + 2 * lane) =
            make_float2((w0 - mu) * rsd * g0 + be0, (w1 - mu) * rsd * g1 + be1);
    }
}

// ---------------------------------------------------------------------------
extern "C" void kernel_launch(void* const* d_in, const int* in_sizes, int n_in,
                              void* d_out, int out_size, void* d_ws, size_t ws_size,
                              hipStream_t stream) {
    const float* x     = (const float*)d_in[0];
    const int*   adj   = (const int*)d_in[1];
    const int*   maskp = (const int*)d_in[2];
    const float* W     = (const float*)d_in[3];
    const float* a_l   = (const float*)d_in[4];
    const float* a_r   = (const float*)d_in[5];
    const float* gamma = (const float*)d_in[6];
    const float* beta  = (const float*)d_in[7];
    float*       outp  = (float*)d_out;

    // ws: hT bf16 (4MB) | el,er f32 | WThi,WTlo bf16
    unsigned short* hT = (unsigned short*)d_ws;
    float* el = (float*)(hT + (size_t)BB * DD * NN);
    float* er = el + (size_t)BB * NN;
    unsigned short* WThi = (unsigned short*)(er + (size_t)BB * NN);
    unsigned short* WTlo = WThi + DD * DD;

    prep_wt<<<64, 256, 0, stream>>>(W, WThi, WTlo);
    fc_kernel<<<BB * (NN / 64), 256, 0, stream>>>(x, maskp, WThi, WTlo,
                                                  a_l, a_r, hT, el, er);
    attn_kernel<<<BB * (NN / 16), 256, 0, stream>>>(x, adj, maskp, hT, el, er,
                                                    gamma, beta, outp);
}

// Round 6
// 289.685 us; speedup vs baseline: 1.1381x; 1.1381x over previous
//
#include <hip/hip_runtime.h>
#include <stdint.h>

// GAT layer, B=8, N=2048, D=128, fp32 in/out.
// prep_wt: W -> W^T bf16 hi/lo (fc B-fragments).
// fc:      h = (x*mask)@W via 3-term bf16-split MFMA -> hT bf16 [B][D][N],
//          e_l, e_r fp32.
// attn:    Phase 1: per-lane VALU bit-pack of adj&mask -> 4KB LDS bitmask
//          (batched independent loads, NO ballot -- R5's ballot serialized
//          on load latency). Phase 2: flash attention (4-way split-K, MFMA
//          bf16 PV) touching only LDS/L1/L2; LDS merge + LayerNorm.

#define BB 8
#define NN 2048
#define DD 128
#define GAT_NEG_INF -10000.0f
#define LN_EPS 1e-5f

typedef __attribute__((ext_vector_type(8))) short short8;
typedef __attribute__((ext_vector_type(4))) float f32x4;

__device__ __forceinline__ unsigned pk_bf16(float a, float b) {
    unsigned ua = __float_as_uint(a); ua += 0x7FFFu + ((ua >> 16) & 1u);
    unsigned ub = __float_as_uint(b); ub += 0x7FFFu + ((ub >> 16) & 1u);
    return (ua >> 16) | (ub & 0xFFFF0000u);
}
__device__ __forceinline__ unsigned short bf16_rtn(float a) {
    unsigned ua = __float_as_uint(a);
    return (unsigned short)((ua + 0x7FFFu + ((ua >> 16) & 1u)) >> 16);
}

// ---------------------------------------------------------------------------
// prep_wt: WThi/WTlo[n][k] = bf16 split of W[k][n].
// ---------------------------------------------------------------------------
__global__ void prep_wt(const float* __restrict__ W,
                        unsigned short* __restrict__ WThi,
                        unsigned short* __restrict__ WTlo)
{
    int idx = blockIdx.x * 256 + threadIdx.x;
    int k = idx >> 7, n = idx & 127;
    float w = W[idx];
    unsigned short hi = bf16_rtn(w);
    float hif = __uint_as_float((unsigned)hi << 16);
    WThi[n * DD + k] = hi;
    WTlo[n * DD + k] = bf16_rtn(w - hif);
}

// ---------------------------------------------------------------------------
// fc: grid = BB*(NN/64) = 256 blocks (b = blk&7), block 256 = 4 waves.
// ---------------------------------------------------------------------------
__global__ __launch_bounds__(256) void fc_kernel(
    const float* __restrict__ x, const int* __restrict__ mask,
    const unsigned short* __restrict__ WThi, const unsigned short* __restrict__ WTlo,
    const float* __restrict__ a_l, const float* __restrict__ a_r,
    unsigned short* __restrict__ hT, float* __restrict__ el, float* __restrict__ er)
{
    const int t    = threadIdx.x;
    const int wv   = t >> 6;
    const int lane = t & 63;
    const int col  = lane & 15;
    const int grp  = lane >> 4;
    const int b    = blockIdx.x & 7;
    const int it   = blockIdx.x >> 3;
    const int i0   = it * 64 + wv * 16;

    const float* xrow = x + ((size_t)(b * NN + i0 + col)) * DD + grp * 8;
    const float  mm   = (float)mask[b * NN + i0 + col];

    f32x4 acc[8];
#pragma unroll
    for (int nb = 0; nb < 8; ++nb) acc[nb] = (f32x4)0.f;

    union AU { unsigned u[4]; short8 v; };
    union BU { int4 q; short8 v; };

#pragma unroll
    for (int ks = 0; ks < 4; ++ks) {
        float4 xa = *(const float4*)(xrow + ks * 32);
        float4 xb = *(const float4*)(xrow + ks * 32 + 4);
        float xv[8] = {xa.x, xa.y, xa.z, xa.w, xb.x, xb.y, xb.z, xb.w};
        unsigned short hi[8]; float lo[8];
#pragma unroll
        for (int u = 0; u < 8; ++u) {
            float v = xv[u] * mm;
            hi[u] = bf16_rtn(v);
            lo[u] = v - __uint_as_float((unsigned)hi[u] << 16);
        }
        AU Ahi, Alo;
#pragma unroll
        for (int j = 0; j < 4; ++j) {
            Ahi.u[j] = (unsigned)hi[2 * j] | ((unsigned)hi[2 * j + 1] << 16);
            Alo.u[j] = pk_bf16(lo[2 * j], lo[2 * j + 1]);
        }
#pragma unroll
        for (int nb = 0; nb < 8; ++nb) {
            BU Bhi, Blo;
            Bhi.q = *(const int4*)(WThi + (nb * 16 + col) * DD + ks * 32 + grp * 8);
            Blo.q = *(const int4*)(WTlo + (nb * 16 + col) * DD + ks * 32 + grp * 8);
            acc[nb] = __builtin_amdgcn_mfma_f32_16x16x32_bf16(Ahi.v, Bhi.v, acc[nb], 0, 0, 0);
            acc[nb] = __builtin_amdgcn_mfma_f32_16x16x32_bf16(Alo.v, Bhi.v, acc[nb], 0, 0, 0);
            acc[nb] = __builtin_amdgcn_mfma_f32_16x16x32_bf16(Ahi.v, Blo.v, acc[nb], 0, 0, 0);
        }
    }

    float sl[4] = {0.f, 0.f, 0.f, 0.f}, sr[4] = {0.f, 0.f, 0.f, 0.f};
#pragma unroll
    for (int nb = 0; nb < 8; ++nb) {
        float alv = a_l[nb * 16 + col];
        float arv = a_r[nb * 16 + col];
#pragma unroll
        for (int reg = 0; reg < 4; ++reg) {
            sl[reg] += acc[nb][reg] * alv;
            sr[reg] += acc[nb][reg] * arv;
        }
    }
#pragma unroll
    for (int off = 1; off < 16; off <<= 1)
#pragma unroll
        for (int reg = 0; reg < 4; ++reg) {
            sl[reg] += __shfl_xor(sl[reg], off, 64);
            sr[reg] += __shfl_xor(sr[reg], off, 64);
        }
    if (col == 0) {
#pragma unroll
        for (int reg = 0; reg < 4; ++reg) {
            el[b * NN + i0 + grp * 4 + reg] = sl[reg];
            er[b * NN + i0 + grp * 4 + reg] = sr[reg];
        }
    }

#pragma unroll
    for (int nb = 0; nb < 8; ++nb) {
        unsigned p01 = pk_bf16(acc[nb][0], acc[nb][1]);
        unsigned p23 = pk_bf16(acc[nb][2], acc[nb][3]);
        *(uint2*)(hT + ((size_t)(b * DD + nb * 16 + col)) * NN + i0 + grp * 4) =
            make_uint2(p01, p23);
    }
}

// ---------------------------------------------------------------------------
// attn: grid = BB*(NN/16) = 1024 blocks (b = blk&7), block 256 = 4 waves.
// Phase 1: thread t (row=t>>4, seg=t&15) reads ints j in [seg*128,seg*128+128)
//          of adj row (i0+row) plus the matching mask ints, packs
//          (adj&mask_j) bits via VALU into 2 u64 -> bitsS[row][seg*2..+1].
//          All loads independent (batches of 8 int4) -> deep MLP, pure stream.
// Phase 2: flash attention. Wave wv: j in [wv*512, wv*512+512), 8 tiles.
//          K-loop data: bitsS (LDS), er (L1, 1-tile prefetch), hT (L2).
// ---------------------------------------------------------------------------
__global__ __launch_bounds__(256, 4) void attn_kernel(
    const float* __restrict__ x, const int* __restrict__ adj,
    const int* __restrict__ mask, const unsigned short* __restrict__ hT,
    const float* __restrict__ el, const float* __restrict__ er,
    const float* __restrict__ gamma, const float* __restrict__ beta,
    float* __restrict__ outp)
{
    __shared__ __align__(16) float macc[4][16][132];        // 33.8 KB
    __shared__ float mls[4][16][2];
    __shared__ unsigned long long bitsS[16][33];            // 4.2 KB

    const int t    = threadIdx.x;
    const int wv   = t >> 6;
    const int lane = t & 63;
    const int row  = lane & 15;
    const int grp  = lane >> 4;
    const int b    = blockIdx.x & 7;
    const int it   = blockIdx.x >> 3;
    const int i0   = it * 16;
    const int gi   = i0 + row;
    const int j0   = wv * 512;

    const int* mk_b    = mask + b * NN;
    const int* adj_blk = adj + ((size_t)(b * NN + i0)) * NN;

    // ---- Phase 1: per-lane VALU bit-pack (no ballot) ----
    {
        const int prow = t >> 4;          // 0..15
        const int seg  = t & 15;          // 0..15
        const int* abase = adj_blk + (size_t)prow * NN + seg * 128;
        const int* mbase = mk_b + seg * 128;
        const int  mi_p  = mk_b[i0 + prow];

        unsigned acc32[4];
#pragma unroll
        for (int c = 0; c < 4; ++c) {       // 4 chunks of 8 int4 (=32 ints)
            int4 a[8], m[8];
#pragma unroll
            for (int g = 0; g < 8; ++g) {
                a[g] = *(const int4*)(abase + (c * 8 + g) * 4);
                m[g] = *(const int4*)(mbase + (c * 8 + g) * 4);
            }
            unsigned part = 0;
#pragma unroll
            for (int g = 0; g < 8; ++g) {
                unsigned nib = (unsigned)((a[g].x & m[g].x) | ((a[g].y & m[g].y) << 1)
                                        | ((a[g].z & m[g].z) << 2) | ((a[g].w & m[g].w) << 3));
                part |= nib << (g * 4);
            }
            acc32[c] = part;
        }
        unsigned long long w0 = ((unsigned long long)acc32[1] << 32) | acc32[0];
        unsigned long long w1 = ((unsigned long long)acc32[3] << 32) | acc32[2];
        if (!mi_p) { w0 = 0ull; w1 = 0ull; }
        bitsS[prow][seg * 2]     = w0;
        bitsS[prow][seg * 2 + 1] = w1;
    }

    const float el_r = el[b * NN + gi];
    const float* er_w = er + b * NN + j0;
    const unsigned short* hT_b = hT + (size_t)b * DD * NN;

    f32x4 acc[8];
#pragma unroll
    for (int nb = 0; nb < 8; ++nb) acc[nb] = (f32x4)0.f;
    float m_run = -3.0e38f, l_run = 0.f;

    __syncthreads();

    union BU { int4 q; short8 v; };
    union AU { unsigned u[4]; short8 v; };

    // er prefetch, one tile ahead
    float4 pe0, pe1, pe2, pe3;
    auto load_er = [&](int jt) {
        const int jb = jt * 64 + grp * 8;
        pe0 = *(const float4*)(er_w + jb);
        pe1 = *(const float4*)(er_w + jb + 4);
        pe2 = *(const float4*)(er_w + jb + 32);
        pe3 = *(const float4*)(er_w + jb + 36);
    };
    load_er(0);

#pragma unroll 1
    for (int jt = 0; jt < 8; ++jt) {
        // B-fragment loads (L2-resident hT)
        BU bf[16];
        {
            const int jb = j0 + jt * 64 + grp * 8;
#pragma unroll
            for (int s = 0; s < 2; ++s)
#pragma unroll
                for (int nb = 0; nb < 8; ++nb)
                    bf[s * 8 + nb].q = *(const int4*)(hT_b
                        + (size_t)(nb * 16 + row) * NN + jb + s * 32);
        }

        float4 e0 = pe0, e1 = pe1, e2 = pe2, e3 = pe3;
        load_er(jt < 7 ? jt + 1 : jt);

        unsigned long long w = bitsS[row][wv * 8 + jt];
        unsigned lo = (unsigned)(w & 0xffffffffu);
        unsigned hi = (unsigned)(w >> 32);
        unsigned b16 = ((lo >> (grp * 8)) & 0xffu) | ((((hi >> (grp * 8)) & 0xffu)) << 8);

        float ev[16] = {e0.x,e0.y,e0.z,e0.w, e1.x,e1.y,e1.z,e1.w,
                        e2.x,e2.y,e2.z,e2.w, e3.x,e3.y,e3.z,e3.w};
        float ss[16];
        float tmax = -3.0e38f;
#pragma unroll
        for (int u = 0; u < 16; ++u) {
            float e = el_r + ev[u];
            e = fmaxf(e, 0.2f * e);                 // LeakyReLU
            ss[u] = ((b16 >> u) & 1u) ? e : GAT_NEG_INF;
            tmax = fmaxf(tmax, ss[u]);
        }
        tmax = fmaxf(tmax, __shfl_xor(tmax, 16, 64));
        tmax = fmaxf(tmax, __shfl_xor(tmax, 32, 64));
        float m_new = fmaxf(m_run, tmax);
        float al    = __expf(m_run - m_new);
        float p[16];
        float psum = 0.f;
#pragma unroll
        for (int u = 0; u < 16; ++u) {
            p[u] = __expf(ss[u] - m_new);
            psum += p[u];
        }
        psum += __shfl_xor(psum, 16, 64);
        psum += __shfl_xor(psum, 32, 64);
        l_run = l_run * al + psum;
        m_run = m_new;

        float alr[4];
#pragma unroll
        for (int reg = 0; reg < 4; ++reg) alr[reg] = __shfl(al, grp * 4 + reg, 64);
#pragma unroll
        for (int nb = 0; nb < 8; ++nb) {
            acc[nb][0] *= alr[0]; acc[nb][1] *= alr[1];
            acc[nb][2] *= alr[2]; acc[nb][3] *= alr[3];
        }

        AU A0, A1;
#pragma unroll
        for (int k = 0; k < 4; ++k) {
            A0.u[k] = pk_bf16(p[2 * k],     p[2 * k + 1]);
            A1.u[k] = pk_bf16(p[8 + 2 * k], p[8 + 2 * k + 1]);
        }
#pragma unroll
        for (int nb = 0; nb < 8; ++nb)
            acc[nb] = __builtin_amdgcn_mfma_f32_16x16x32_bf16(A0.v, bf[nb].v, acc[nb], 0, 0, 0);
#pragma unroll
        for (int nb = 0; nb < 8; ++nb)
            acc[nb] = __builtin_amdgcn_mfma_f32_16x16x32_bf16(A1.v, bf[8 + nb].v, acc[nb], 0, 0, 0);
    }

    // ---- write partials to LDS ----
    if (grp == 0) { mls[wv][row][0] = m_run; mls[wv][row][1] = l_run; }
#pragma unroll
    for (int nb = 0; nb < 8; ++nb)
#pragma unroll
        for (int reg = 0; reg < 4; ++reg)
            macc[wv][grp * 4 + reg][nb * 16 + row] = acc[nb][reg];
    __syncthreads();

    // ---- merge + residual + mask + LayerNorm; wave wv owns rows wv*4..+3 ----
    const float g0  = gamma[2 * lane], g1 = gamma[2 * lane + 1];
    const float be0 = beta[2 * lane],  be1 = beta[2 * lane + 1];
#pragma unroll
    for (int q = 0; q < 4; ++q) {
        const int r  = wv * 4 + q;
        const int gir = i0 + r;
        float m0 = mls[0][r][0], m1 = mls[1][r][0], m2 = mls[2][r][0], m3 = mls[3][r][0];
        float m_f = fmaxf(fmaxf(m0, m1), fmaxf(m2, m3));
        float sc0 = __expf(m0 - m_f), sc1 = __expf(m1 - m_f);
        float sc2 = __expf(m2 - m_f), sc3 = __expf(m3 - m_f);
        float l_f = mls[0][r][1] * sc0 + mls[1][r][1] * sc1
                  + mls[2][r][1] * sc2 + mls[3][r][1] * sc3;
        float inv = 1.0f / l_f;
        float2 v0 = *(const float2*)&macc[0][r][2 * lane];
        float2 v1 = *(const float2*)&macc[1][r][2 * lane];
        float2 v2 = *(const float2*)&macc[2][r][2 * lane];
        float2 v3 = *(const float2*)&macc[3][r][2 * lane];
        float ox = v0.x * sc0 + v1.x * sc1 + v2.x * sc2 + v3.x * sc3;
        float oy = v0.y * sc0 + v1.y * sc1 + v2.y * sc2 + v3.y * sc3;

        float mq = (float)mk_b[gir];
        float2 xv = *(const float2*)(x + ((size_t)(b * NN + gir)) * DD + 2 * lane);
        float w0 = (ox * inv + xv.x) * mq;
        float w1 = (oy * inv + xv.y) * mq;

        float s1 = w0 + w1, s2 = w0 * w0 + w1 * w1;
#pragma unroll
        for (int off = 32; off; off >>= 1) {
            s1 += __shfl_xor(s1, off, 64);
            s2 += __shfl_xor(s2, off, 64);
        }
        float mu  = s1 * (1.0f / DD);
        float var = s2 * (1.0f / DD) - mu * mu;
        float rsd = rsqrtf(var + LN_EPS);
        *(float2*)(outp + ((size_t)(b * NN + gir)) * DD + 2 * lane) =
            make_float2((w0 - mu) * rsd * g0 + be0, (w1 - mu) * rsd * g1 + be1);
    }
}

// ---------------------------------------------------------------------------
extern "C" void kernel_launch(void* const* d_in, const int* in_sizes, int n_in,
                              void* d_out, int out_size, void* d_ws, size_t ws_size,
                              hipStream_t stream) {
    const float* x     = (const float*)d_in[0];
    const int*   adj   = (const int*)d_in[1];
    const int*   maskp = (const int*)d_in[2];
    const float* W     = (const float*)d_in[3];
    const float* a_l   = (const float*)d_in[4];
    const float* a_r   = (const float*)d_in[5];
    const float* gamma = (const float*)d_in[6];
    const float* beta  = (const float*)d_in[7];
    float*       outp  = (float*)d_out;

    // ws: hT bf16 (4MB) | el,er f32 | WThi,WTlo bf16
    unsigned short* hT = (unsigned short*)d_ws;
    float* el = (float*)(hT + (size_t)BB * DD * NN);
    float* er = el + (size_t)BB * NN;
    unsigned short* WThi = (unsigned short*)(er + (size_t)BB * NN);
    unsigned short* WTlo = WThi + DD * DD;

    prep_wt<<<64, 256, 0, stream>>>(W, WThi, WTlo);
    fc_kernel<<<BB * (NN / 64), 256, 0, stream>>>(x, maskp, WThi, WTlo,
                                                  a_l, a_r, hT, el, er);
    attn_kernel<<<BB * (NN / 16), 256, 0, stream>>>(x, adj, maskp, hT, el, er,
                                                    gamma, beta, outp);
}

// Round 7
// 289.247 us; speedup vs baseline: 1.1398x; 1.0015x over previous
//
#include <hip/hip_runtime.h>
#include <stdint.h>

// GAT layer, B=8, N=2048, D=128, fp32 in/out.
// prep_wt: W -> W^T bf16 hi/lo (fc B-fragments).
// fc:      h = (x*mask)@W via 3-term bf16-split MFMA -> hT bf16 [B][D][N],
//          e_l, e_r fp32.
// attn:    Phase 1: wave-contiguous adj loads (1KB/instr, full lines) +
//          shuffle-transpose bit-pack -> 4KB LDS bitmask. Phase 2: flash
//          attention (4-way split-K, MFMA bf16 PV), LDS merge + LayerNorm.

#define BB 8
#define NN 2048
#define DD 128
#define GAT_NEG_INF -10000.0f
#define LN_EPS 1e-5f

typedef __attribute__((ext_vector_type(8))) short short8;
typedef __attribute__((ext_vector_type(4))) float f32x4;

__device__ __forceinline__ unsigned pk_bf16(float a, float b) {
    unsigned ua = __float_as_uint(a); ua += 0x7FFFu + ((ua >> 16) & 1u);
    unsigned ub = __float_as_uint(b); ub += 0x7FFFu + ((ub >> 16) & 1u);
    return (ua >> 16) | (ub & 0xFFFF0000u);
}
__device__ __forceinline__ unsigned short bf16_rtn(float a) {
    unsigned ua = __float_as_uint(a);
    return (unsigned short)((ua + 0x7FFFu + ((ua >> 16) & 1u)) >> 16);
}

// ---------------------------------------------------------------------------
// prep_wt: WThi/WTlo[n][k] = bf16 split of W[k][n].
// ---------------------------------------------------------------------------
__global__ void prep_wt(const float* __restrict__ W,
                        unsigned short* __restrict__ WThi,
                        unsigned short* __restrict__ WTlo)
{
    int idx = blockIdx.x * 256 + threadIdx.x;
    int k = idx >> 7, n = idx & 127;
    float w = W[idx];
    unsigned short hi = bf16_rtn(w);
    float hif = __uint_as_float((unsigned)hi << 16);
    WThi[n * DD + k] = hi;
    WTlo[n * DD + k] = bf16_rtn(w - hif);
}

// ---------------------------------------------------------------------------
// fc: grid = BB*(NN/64) = 256 blocks (b = blk&7), block 256 = 4 waves.
// ---------------------------------------------------------------------------
__global__ __launch_bounds__(256) void fc_kernel(
    const float* __restrict__ x, const int* __restrict__ mask,
    const unsigned short* __restrict__ WThi, const unsigned short* __restrict__ WTlo,
    const float* __restrict__ a_l, const float* __restrict__ a_r,
    unsigned short* __restrict__ hT, float* __restrict__ el, float* __restrict__ er)
{
    const int t    = threadIdx.x;
    const int wv   = t >> 6;
    const int lane = t & 63;
    const int col  = lane & 15;
    const int grp  = lane >> 4;
    const int b    = blockIdx.x & 7;
    const int it   = blockIdx.x >> 3;
    const int i0   = it * 64 + wv * 16;

    const float* xrow = x + ((size_t)(b * NN + i0 + col)) * DD + grp * 8;
    const float  mm   = (float)mask[b * NN + i0 + col];

    f32x4 acc[8];
#pragma unroll
    for (int nb = 0; nb < 8; ++nb) acc[nb] = (f32x4)0.f;

    union AU { unsigned u[4]; short8 v; };
    union BU { int4 q; short8 v; };

#pragma unroll
    for (int ks = 0; ks < 4; ++ks) {
        float4 xa = *(const float4*)(xrow + ks * 32);
        float4 xb = *(const float4*)(xrow + ks * 32 + 4);
        float xv[8] = {xa.x, xa.y, xa.z, xa.w, xb.x, xb.y, xb.z, xb.w};
        unsigned short hi[8]; float lo[8];
#pragma unroll
        for (int u = 0; u < 8; ++u) {
            float v = xv[u] * mm;
            hi[u] = bf16_rtn(v);
            lo[u] = v - __uint_as_float((unsigned)hi[u] << 16);
        }
        AU Ahi, Alo;
#pragma unroll
        for (int j = 0; j < 4; ++j) {
            Ahi.u[j] = (unsigned)hi[2 * j] | ((unsigned)hi[2 * j + 1] << 16);
            Alo.u[j] = pk_bf16(lo[2 * j], lo[2 * j + 1]);
        }
#pragma unroll
        for (int nb = 0; nb < 8; ++nb) {
            BU Bhi, Blo;
            Bhi.q = *(const int4*)(WThi + (nb * 16 + col) * DD + ks * 32 + grp * 8);
            Blo.q = *(const int4*)(WTlo + (nb * 16 + col) * DD + ks * 32 + grp * 8);
            acc[nb] = __builtin_amdgcn_mfma_f32_16x16x32_bf16(Ahi.v, Bhi.v, acc[nb], 0, 0, 0);
            acc[nb] = __builtin_amdgcn_mfma_f32_16x16x32_bf16(Alo.v, Bhi.v, acc[nb], 0, 0, 0);
            acc[nb] = __builtin_amdgcn_mfma_f32_16x16x32_bf16(Ahi.v, Blo.v, acc[nb], 0, 0, 0);
        }
    }

    float sl[4] = {0.f, 0.f, 0.f, 0.f}, sr[4] = {0.f, 0.f, 0.f, 0.f};
#pragma unroll
    for (int nb = 0; nb < 8; ++nb) {
        float alv = a_l[nb * 16 + col];
        float arv = a_r[nb * 16 + col];
#pragma unroll
        for (int reg = 0; reg < 4; ++reg) {
            sl[reg] += acc[nb][reg] * alv;
            sr[reg] += acc[nb][reg] * arv;
        }
    }
#pragma unroll
    for (int off = 1; off < 16; off <<= 1)
#pragma unroll
        for (int reg = 0; reg < 4; ++reg) {
            sl[reg] += __shfl_xor(sl[reg], off, 64);
            sr[reg] += __shfl_xor(sr[reg], off, 64);
        }
    if (col == 0) {
#pragma unroll
        for (int reg = 0; reg < 4; ++reg) {
            el[b * NN + i0 + grp * 4 + reg] = sl[reg];
            er[b * NN + i0 + grp * 4 + reg] = sr[reg];
        }
    }

#pragma unroll
    for (int nb = 0; nb < 8; ++nb) {
        unsigned p01 = pk_bf16(acc[nb][0], acc[nb][1]);
        unsigned p23 = pk_bf16(acc[nb][2], acc[nb][3]);
        *(uint2*)(hT + ((size_t)(b * DD + nb * 16 + col)) * NN + i0 + grp * 4) =
            make_uint2(p01, p23);
    }
}

// ---------------------------------------------------------------------------
// attn: grid = BB*(NN/16) = 1024 blocks (b = blk&7), block 256 = 4 waves.
// Phase 1: wave wv packs rows wv*4..+3. Lane l loads int4 (adj ints 4l..4l+3)
//          at 8 segment offsets (each wave instr = 1KB contiguous). Bits
//          merged across lanes via shfl_xor(1,2,4) + partner(8) -> u64,
//          written by lanes l%16==0 to bitsS. mask_j ANDed from 8 hoisted
//          int4 (L1-hot); mask_i applied in phase 2.
// Phase 2: flash attention. Wave wv: j in [wv*512, wv*512+512), 8 tiles.
//          K-loop data: bitsS (LDS), er (L1, prefetch), hT (L2).
// ---------------------------------------------------------------------------
__global__ __launch_bounds__(256, 4) void attn_kernel(
    const float* __restrict__ x, const int* __restrict__ adj,
    const int* __restrict__ mask, const unsigned short* __restrict__ hT,
    const float* __restrict__ el, const float* __restrict__ er,
    const float* __restrict__ gamma, const float* __restrict__ beta,
    float* __restrict__ outp)
{
    __shared__ __align__(16) float macc[4][16][132];        // 33.8 KB
    __shared__ float mls[4][16][2];
    __shared__ unsigned long long bitsS[16][33];            // 4.2 KB

    const int t    = threadIdx.x;
    const int wv   = t >> 6;
    const int lane = t & 63;
    const int row  = lane & 15;
    const int grp  = lane >> 4;
    const int b    = blockIdx.x & 7;
    const int it   = blockIdx.x >> 3;
    const int i0   = it * 16;
    const int gi   = i0 + row;
    const int j0   = wv * 512;

    const int* mk_b    = mask + b * NN;
    const int* adj_blk = adj + ((size_t)(b * NN + i0)) * NN;

    // ---- Phase 1: coalesced loads + shuffle-transpose bit-pack ----
    {
        int4 mreg[8];
#pragma unroll
        for (int ld = 0; ld < 8; ++ld)
            mreg[ld] = *(const int4*)(mk_b + ld * 256 + lane * 4);
#pragma unroll
        for (int rr = 0; rr < 4; ++rr) {
            const int prow = wv * 4 + rr;
            const int* arow = adj_blk + (size_t)prow * NN + lane * 4;
            int4 areg[8];
#pragma unroll
            for (int ld = 0; ld < 8; ++ld)
                areg[ld] = *(const int4*)(arow + ld * 256);
#pragma unroll
            for (int ld = 0; ld < 8; ++ld) {
                int4 a = areg[ld], m = mreg[ld];
                unsigned nib = (unsigned)((a.x & m.x) | ((a.y & m.y) << 1)
                                        | ((a.z & m.z) << 2) | ((a.w & m.w) << 3));
                unsigned v = nib << ((lane & 7) * 4);
                v |= __shfl_xor(v, 1, 64);
                v |= __shfl_xor(v, 2, 64);
                v |= __shfl_xor(v, 4, 64);
                unsigned o = __shfl_xor(v, 8, 64);
                unsigned long long w = (lane & 8)
                    ? (((unsigned long long)v << 32) | o)
                    : (((unsigned long long)o << 32) | v);
                if ((lane & 15) == 0)
                    bitsS[prow][ld * 4 + (lane >> 4)] = w;
            }
        }
    }

    const float el_r = el[b * NN + gi];
    const int   mi   = mk_b[gi];
    const unsigned mi_msk = mi ? 0xffffu : 0u;
    const float* er_w = er + b * NN + j0;
    const unsigned short* hT_b = hT + (size_t)b * DD * NN;

    f32x4 acc[8];
#pragma unroll
    for (int nb = 0; nb < 8; ++nb) acc[nb] = (f32x4)0.f;
    float m_run = -3.0e38f, l_run = 0.f;

    __syncthreads();

    union BU { int4 q; short8 v; };
    union AU { unsigned u[4]; short8 v; };

    // er prefetch, one tile ahead
    float4 pe0, pe1, pe2, pe3;
    auto load_er = [&](int jt) {
        const int jb = jt * 64 + grp * 8;
        pe0 = *(const float4*)(er_w + jb);
        pe1 = *(const float4*)(er_w + jb + 4);
        pe2 = *(const float4*)(er_w + jb + 32);
        pe3 = *(const float4*)(er_w + jb + 36);
    };
    load_er(0);

#pragma unroll 1
    for (int jt = 0; jt < 8; ++jt) {
        // B-fragment loads (L2-resident hT)
        BU bf[16];
        {
            const int jb = j0 + jt * 64 + grp * 8;
#pragma unroll
            for (int s = 0; s < 2; ++s)
#pragma unroll
                for (int nb = 0; nb < 8; ++nb)
                    bf[s * 8 + nb].q = *(const int4*)(hT_b
                        + (size_t)(nb * 16 + row) * NN + jb + s * 32);
        }

        float4 e0 = pe0, e1 = pe1, e2 = pe2, e3 = pe3;
        load_er(jt < 7 ? jt + 1 : jt);

        unsigned long long w = bitsS[row][wv * 8 + jt];
        unsigned lo = (unsigned)(w & 0xffffffffu);
        unsigned hi = (unsigned)(w >> 32);
        unsigned b16 = ((lo >> (grp * 8)) & 0xffu) | ((((hi >> (grp * 8)) & 0xffu)) << 8);
        b16 &= mi_msk;

        float ev[16] = {e0.x,e0.y,e0.z,e0.w, e1.x,e1.y,e1.z,e1.w,
                        e2.x,e2.y,e2.z,e2.w, e3.x,e3.y,e3.z,e3.w};
        float ss[16];
        float tmax = -3.0e38f;
#pragma unroll
        for (int u = 0; u < 16; ++u) {
            float e = el_r + ev[u];
            e = fmaxf(e, 0.2f * e);                 // LeakyReLU
            ss[u] = ((b16 >> u) & 1u) ? e : GAT_NEG_INF;
            tmax = fmaxf(tmax, ss[u]);
        }
        tmax = fmaxf(tmax, __shfl_xor(tmax, 16, 64));
        tmax = fmaxf(tmax, __shfl_xor(tmax, 32, 64));
        float m_new = fmaxf(m_run, tmax);
        float al    = __expf(m_run - m_new);
        float p[16];
        float psum = 0.f;
#pragma unroll
        for (int u = 0; u < 16; ++u) {
            p[u] = __expf(ss[u] - m_new);
            psum += p[u];
        }
        psum += __shfl_xor(psum, 16, 64);
        psum += __shfl_xor(psum, 32, 64);
        l_run = l_run * al + psum;
        m_run = m_new;

        float alr[4];
#pragma unroll
        for (int reg = 0; reg < 4; ++reg) alr[reg] = __shfl(al, grp * 4 + reg, 64);
#pragma unroll
        for (int nb = 0; nb < 8; ++nb) {
            acc[nb][0] *= alr[0]; acc[nb][1] *= alr[1];
            acc[nb][2] *= alr[2]; acc[nb][3] *= alr[3];
        }

        AU A0, A1;
#pragma unroll
        for (int k = 0; k < 4; ++k) {
            A0.u[k] = pk_bf16(p[2 * k],     p[2 * k + 1]);
            A1.u[k] = pk_bf16(p[8 + 2 * k], p[8 + 2 * k + 1]);
        }
#pragma unroll
        for (int nb = 0; nb < 8; ++nb)
            acc[nb] = __builtin_amdgcn_mfma_f32_16x16x32_bf16(A0.v, bf[nb].v, acc[nb], 0, 0, 0);
#pragma unroll
        for (int nb = 0; nb < 8; ++nb)
            acc[nb] = __builtin_amdgcn_mfma_f32_16x16x32_bf16(A1.v, bf[8 + nb].v, acc[nb], 0, 0, 0);
    }

    // ---- write partials to LDS ----
    if (grp == 0) { mls[wv][row][0] = m_run; mls[wv][row][1] = l_run; }
#pragma unroll
    for (int nb = 0; nb < 8; ++nb)
#pragma unroll
        for (int reg = 0; reg < 4; ++reg)
            macc[wv][grp * 4 + reg][nb * 16 + row] = acc[nb][reg];
    __syncthreads();

    // ---- merge + residual + mask + LayerNorm; wave wv owns rows wv*4..+3 ----
    const float g0  = gamma[2 * lane], g1 = gamma[2 * lane + 1];
    const float be0 = beta[2 * lane],  be1 = beta[2 * lane + 1];
#pragma unroll
    for (int q = 0; q < 4; ++q) {
        const int r  = wv * 4 + q;
        const int gir = i0 + r;
        float m0 = mls[0][r][0], m1 = mls[1][r][0], m2 = mls[2][r][0], m3 = mls[3][r][0];
        float m_f = fmaxf(fmaxf(m0, m1), fmaxf(m2, m3));
        float sc0 = __expf(m0 - m_f), sc1 = __expf(m1 - m_f);
        float sc2 = __expf(m2 - m_f), sc3 = __expf(m3 - m_f);
        float l_f = mls[0][r][1] * sc0 + mls[1][r][1] * sc1
                  + mls[2][r][1] * sc2 + mls[3][r][1] * sc3;
        float inv = 1.0f / l_f;
        float2 v0 = *(const float2*)&macc[0][r][2 * lane];
        float2 v1 = *(const float2*)&macc[1][r][2 * lane];
        float2 v2 = *(const float2*)&macc[2][r][2 * lane];
        float2 v3 = *(const float2*)&macc[3][r][2 * lane];
        float ox = v0.x * sc0 + v1.x * sc1 + v2.x * sc2 + v3.x * sc3;
        float oy = v0.y * sc0 + v1.y * sc1 + v2.y * sc2 + v3.y * sc3;

        float mq = (float)mk_b[gir];
        float2 xv = *(const float2*)(x + ((size_t)(b * NN + gir)) * DD + 2 * lane);
        float w0 = (ox * inv + xv.x) * mq;
        float w1 = (oy * inv + xv.y) * mq;

        float s1 = w0 + w1, s2 = w0 * w0 + w1 * w1;
#pragma unroll
        for (int off = 32; off; off >>= 1) {
            s1 += __shfl_xor(s1, off, 64);
            s2 += __shfl_xor(s2, off, 64);
        }
        float mu  = s1 * (1.0f / DD);
        float var = s2 * (1.0f / DD) - mu * mu;
        float rsd = rsqrtf(var + LN_EPS);
        *(float2*)(outp + ((size_t)(b * NN + gir)) * DD + 2 * lane) =
            make_float2((w0 - mu) * rsd * g0 + be0, (w1 - mu) * rsd * g1 + be1);
    }
}

// ---------------------------------------------------------------------------
extern "C" void kernel_launch(void* const* d_in, const int* in_sizes, int n_in,
                              void* d_out, int out_size, void* d_ws, size_t ws_size,
                              hipStream_t stream) {
    const float* x     = (const float*)d_in[0];
    const int*   adj   = (const int*)d_in[1];
    const int*   maskp = (const int*)d_in[2];
    const float* W     = (const float*)d_in[3];
    const float* a_l   = (const float*)d_in[4];
    const float* a_r   = (const float*)d_in[5];
    const float* gamma = (const float*)d_in[6];
    const float* beta  = (const float*)d_in[7];
    float*       outp  = (float*)d_out;

    // ws: hT bf16 (4MB) | el,er f32 | WThi,WTlo bf16
    unsigned short* hT = (unsigned short*)d_ws;
    float* el = (float*)(hT + (size_t)BB * DD * NN);
    float* er = el + (size_t)BB * NN;
    unsigned short* WThi = (unsigned short*)(er + (size_t)BB * NN);
    unsigned short* WTlo = WThi + DD * DD;

    prep_wt<<<64, 256, 0, stream>>>(W, WThi, WTlo);
    fc_kernel<<<BB * (NN / 64), 256, 0, stream>>>(x, maskp, WThi, WTlo,
                                                  a_l, a_r, hT, el, er);
    attn_kernel<<<BB * (NN / 16), 256, 0, stream>>>(x, adj, maskp, hT, el, er,
                                                    gamma, beta, outp);
}